// Round 8
// baseline (382.136 us; speedup 1.0000x reference)
//
#include <hip/hip_runtime.h>
#include <hip/hip_bf16.h>
#include <cstdint>

#define N_ROWS 4096
#define N_CLS  8192
#define D_EMB  512
#define K_DIM  1024   // bytes per row: [x^2 s-channel 512][2x ps-channel 512]

using f32x4  = __attribute__((ext_vector_type(4)))  float;
using f32x16 = __attribute__((ext_vector_type(16))) float;
using i32x8  = __attribute__((ext_vector_type(8)))  int;

__device__ __forceinline__ float softplus_f(float v) {
  return (v > 20.f) ? v : log1pf(expf(v));
}

// pack 2 f32 -> 2 fp8 e4m3 (OCP, RNE) in low 16 bits
__device__ __forceinline__ unsigned short pack2_e4m3(float a, float b) {
  return (unsigned short)(__builtin_amdgcn_cvt_pk_fp8_f32(a, b, 0, false) & 0xffff);
}

__device__ __forceinline__ float e4m3_to_f(unsigned char v) {
  int e = (v >> 3) & 15, m = v & 7;
  float f;
  if (e) f = __uint_as_float((unsigned int)((e + 120) << 23) | ((unsigned int)m << 20));
  else   f = (float)m * 0.001953125f;   // m * 2^-9
  return (v & 0x80) ? -f : f;
}

// block-wide sum for 256 threads (4 waves); re-entrant (syncs guard the LDS)
__device__ __forceinline__ float block_sum256(float v) {
  __shared__ float red[4];
  #pragma unroll
  for (int o = 32; o; o >>= 1) v += __shfl_xor(v, o);
  __syncthreads();
  if ((threadIdx.x & 63) == 0) red[threadIdx.x >> 6] = v;
  __syncthreads();
  return red[0] + red[1] + red[2] + red[3];
}

__device__ __forceinline__ void global_to_lds16(const void* g, void* l) {
  const __attribute__((address_space(1))) unsigned int* gp =
      reinterpret_cast<const __attribute__((address_space(1))) unsigned int*>(
          reinterpret_cast<uintptr_t>(g));
  __attribute__((address_space(3))) unsigned int* lp =
      reinterpret_cast<__attribute__((address_space(3))) unsigned int*>(
          reinterpret_cast<uintptr_t>(l));
  __builtin_amdgcn_global_load_lds(gp, lp, 16, 0, 0);
}

// ---------------------------------------------------------------------------
// K1: fused prep. Blocks [0, N_CLS): per-class -> Bmat fp8 [s | P*s], tvec,
//     klc. Blocks [N_CLS, N_CLS+N_ROWS): per-row -> Amat fp8 [-Xn^2 | 2Xn].
// ---------------------------------------------------------------------------
__global__ __launch_bounds__(256) void k_prep(const float* __restrict__ proxies,
                                              const float* __restrict__ sigmas_inv,
                                              const float* __restrict__ X,
                                              unsigned char* __restrict__ Bmat,
                                              unsigned char* __restrict__ Amat,
                                              float* __restrict__ tvec,
                                              float* __restrict__ klc) {
  const int bid = blockIdx.x;
  const int tid = threadIdx.x;
  if (bid < N_CLS) {
    const int c = bid;
    const float* p  = proxies    + (size_t)c * D_EMB;
    const float* si = sigmas_inv + (size_t)c * D_EMB;
    float2 p2 = ((const float2*)p)[tid];
    float ss = block_sum256(p2.x * p2.x + p2.y * p2.y);
    float invn = 1.0f / fmaxf(sqrtf(ss), 1e-12f);
    float2 s2 = ((const float2*)si)[tid];
    float sp0 = softplus_f(s2.x), sp1 = softplus_f(s2.y);
    float s0 = sp0 * sp0, s1 = sp1 * sp1;
    float pn0 = p2.x * invn, pn1 = p2.y * invn;
    float P0 = 3.0f * pn0, P1 = 3.0f * pn1;
    unsigned short* brow = (unsigned short*)(Bmat + (size_t)c * K_DIM);
    brow[tid]       = pack2_e4m3(s0, s1);
    brow[256 + tid] = pack2_e4m3(P0 * s0, P1 * s1);
    float tc = P0 * P0 * s0 + P1 * P1 * s1;
    float kl = 0.5f * (1.0f / s0 + pn0 * pn0 - 1.0f + 2.0f * logf(sp0))
             + 0.5f * (1.0f / s1 + pn1 * pn1 - 1.0f + 2.0f * logf(sp1));
    tc = block_sum256(tc);
    kl = block_sum256(kl);
    if (tid == 0) { tvec[c] = tc; klc[c] = kl; }
  } else {
    const int n = bid - N_CLS;
    const float* x = X + (size_t)n * D_EMB;
    float2 x2 = ((const float2*)x)[tid];
    float ss = block_sum256(x2.x * x2.x + x2.y * x2.y);
    float invn = 3.0f / fmaxf(sqrtf(ss), 1e-12f);   // SCALE folded in
    float v0 = x2.x * invn, v1 = x2.y * invn;
    unsigned short* arow = (unsigned short*)(Amat + (size_t)n * K_DIM);
    arow[tid]       = pack2_e4m3(-v0 * v0, -v1 * v1);
    arow[256 + tid] = pack2_e4m3(2.0f * v0, 2.0f * v1);
  }
}

// ---------------------------------------------------------------------------
// K3: 256x128-tile MX-fp8 GEMM using mfma_scale_f32_32x32x64_f8f6f4 with unit
//     scales (numerically == plain fp8 e4m3 dot, 2x MFMA rate). 8 waves
//     (4M x 2N, 64x64/wave), BK=64, 2-slot LDS, stage-then-compute pipeline.
//     LDS is laid out in FRAGMENT ORDER: region F(i) holds one 32-row (or
//     32-col) MFMA fragment as lane*32 contiguous bytes, so ds_reads are
//     base+lane*32 (2-way bank alias = free, zero per-iter address VALU).
//     The global source of each global_load_lds is pre-permuted to match.
//     Fused per-row max/sumexp epilogue -> Pm/Psum[n][64].
// ---------------------------------------------------------------------------
__global__ __launch_bounds__(512, 4) void k_gemm_lse(const unsigned char* __restrict__ Amat,
                                                     const unsigned char* __restrict__ Bmat,
                                                     const float* __restrict__ tvec,
                                                     float* __restrict__ Pm,
                                                     float* __restrict__ Psum) {
  // slot s (24576 B): As = 8 frag-regions x 2048 B at s*24576,
  //                   Bs = 4 frag-regions x 2048 B at s*24576 + 16384.
  // Epilogue ms[256][2][2] (4 KB) overlays slot 0; last compute reads slot 1.
  __shared__ __align__(16) unsigned char lds[49152];
  const int tid  = threadIdx.x;
  const int lane = tid & 63;
  const int wave = tid >> 6;
  const int wr = wave >> 1, wc = wave & 1;          // 4x2 wave grid; 64x64/wave
  // T1: chunked XCD swizzle. nwg=1024, 128 consecutive per XCD; rt fastest.
  const int swz  = ((int)blockIdx.x & 7) * 128 + ((int)blockIdx.x >> 3);
  const int rt   = swz & 15;                        // 16 row tiles (256 rows)
  const int ct   = swz >> 4;                        // 64 col tiles (128 cols)
  const int row0 = rt * 256;
  const int col0 = ct * 128;

  const f32x16 Z = {0.f,0.f,0.f,0.f, 0.f,0.f,0.f,0.f, 0.f,0.f,0.f,0.f, 0.f,0.f,0.f,0.f};
  f32x16 acc00 = Z, acc01 = Z, acc10 = Z, acc11 = Z;

  // ---- staging sources (global addr pre-permuted into fragment order) ----
  // A: chunk g in [0,1024): mi=g>>7, l=(g&127)>>1, h=g&1
  //    src = A[row0 + mi*32 + (l&31)][(l>>5)*32 + h*16 ...], dst = g*16.
  const int gA0i = tid, gA1i = 512 + tid, gBi = tid;
  auto srcA = [&](int g) {
    int mi = g >> 7, l = (g & 127) >> 1, h = g & 1;
    return Amat + (size_t)(row0 + mi * 32 + (l & 31)) * K_DIM + (l >> 5) * 32 + h * 16;
  };
  auto srcB = [&](int g) {
    int nj = g >> 7, l = (g & 127) >> 1, h = g & 1;
    return Bmat + (size_t)(col0 + nj * 32 + (l & 31)) * K_DIM + (l >> 5) * 32 + h * 16;
  };
  const unsigned char* gA0 = srcA(gA0i);
  const unsigned char* gA1 = srcA(gA1i);
  const unsigned char* gB0 = srcB(gBi);

  auto stg = [&](int slot, int ko) {                // 3 x 16B loads / thread
    unsigned char* base = lds + slot * 24576;
    global_to_lds16(gA0 + ko, base + gA0i * 16);
    global_to_lds16(gA1 + ko, base + gA1i * 16);
    global_to_lds16(gB0 + ko, base + 16384 + gBi * 16);
  };

  // fragment read offsets (compile-time + lane*32)
  const int la32 = lane * 32;
  const int offA0 = (wr * 2 + 0) * 2048 + la32;
  const int offA1 = (wr * 2 + 1) * 2048 + la32;
  const int offB0 = 16384 + (wc * 2 + 0) * 2048 + la32;
  const int offB1 = 16384 + (wc * 2 + 1) * 2048 + la32;

  stg(0, 0);
  __syncthreads();
  for (int t = 0; t < 16; ++t) {
    if (t < 15) stg((t + 1) & 1, (t + 1) * 64);     // issue next-tile loads FIRST
    const unsigned char* S = lds + (t & 1) * 24576;
    i32x8 a0 = *(const i32x8*)(S + offA0);
    i32x8 a1 = *(const i32x8*)(S + offA1);
    i32x8 b0 = *(const i32x8*)(S + offB0);
    i32x8 b1 = *(const i32x8*)(S + offB1);
    __builtin_amdgcn_s_setprio(1);
    acc00 = __builtin_amdgcn_mfma_scale_f32_32x32x64_f8f6f4(a0, b0, acc00, 0, 0, 0, 0x7f7f7f7f, 0, 0x7f7f7f7f);
    acc01 = __builtin_amdgcn_mfma_scale_f32_32x32x64_f8f6f4(a0, b1, acc01, 0, 0, 0, 0x7f7f7f7f, 0, 0x7f7f7f7f);
    acc10 = __builtin_amdgcn_mfma_scale_f32_32x32x64_f8f6f4(a1, b0, acc10, 0, 0, 0, 0x7f7f7f7f, 0, 0x7f7f7f7f);
    acc11 = __builtin_amdgcn_mfma_scale_f32_32x32x64_f8f6f4(a1, b1, acc11, 0, 0, 0, 0x7f7f7f7f, 0, 0x7f7f7f7f);
    __builtin_amdgcn_s_setprio(0);
    __syncthreads();   // drains staging vmcnt AFTER compute: latency hidden
  }

  // ---- epilogue: per-row max / sumexp over this wave's 64 cols.
  // 32x32 C/D layout: col = lane&31, row = (r&3) + 8*(r>>2) + 4*(lane>>5).
  float (*ms)[2][2] = (float (*)[2][2])lds;   // overlays slot 0; slot 1 was last read
  const float tc0 = tvec[col0 + wc * 64 + (lane & 31)];
  const float tc1 = tvec[col0 + wc * 64 + 32 + (lane & 31)];
  const int rbase = (lane >> 5) * 4;   // row contribution from lane-half

  #pragma unroll
  for (int tm = 0; tm < 2; ++tm) {
    const f32x16& CA = tm ? acc10 : acc00;
    const f32x16& CB = tm ? acc11 : acc01;
    #pragma unroll
    for (int r = 0; r < 16; ++r) {
      float z0 = CA[r] - tc0;
      float z1 = CB[r] - tc1;
      float m = fmaxf(z0, z1);
      #pragma unroll
      for (int o = 1; o < 32; o <<= 1) m = fmaxf(m, __shfl_xor(m, o));
      float s = __expf(z0 - m) + __expf(z1 - m);
      #pragma unroll
      for (int o = 1; o < 32; o <<= 1) s += __shfl_xor(s, o);
      if ((lane & 31) == 0) {
        int rloc = wr * 64 + tm * 32 + (r & 3) + 8 * (r >> 2) + rbase;
        ms[rloc][wc][0] = m;
        ms[rloc][wc][1] = s;
      }
    }
  }
  __syncthreads();
  if (tid < 256) {
    float m0 = ms[tid][0][0], s0 = ms[tid][0][1];
    float m1 = ms[tid][1][0], s1 = ms[tid][1][1];
    float M = fmaxf(m0, m1);
    float S = s0 * __expf(m0 - M) + s1 * __expf(m1 - M);
    Pm  [(size_t)(row0 + tid) * 64 + ct] = M;
    Psum[(size_t)(row0 + tid) * 64 + ct] = S;
  }
}

// ---------------------------------------------------------------------------
// K5a: 256-block reduce, target-dot FUSED. Block b:
//      phase 1: rows [b*16, b*16+16): tgt[n] = A[n]·B[T[n]] - t[T[n]]
//      phase 2: same rows -> LSE over 64 partials -> ce partial;
//               classes [b*32, b*32+32) -> kl partial.
// ---------------------------------------------------------------------------
__global__ __launch_bounds__(256) void k_red(const float* __restrict__ Pm,
                                             const float* __restrict__ Psum,
                                             const unsigned char* __restrict__ Amat,
                                             const unsigned char* __restrict__ Bmat,
                                             const float* __restrict__ tvec,
                                             const int* __restrict__ T,
                                             const float* __restrict__ klc,
                                             float* __restrict__ cep,
                                             float* __restrict__ klp) {
  __shared__ float tgt_s[16];
  const int b = blockIdx.x;
  const int tid = threadIdx.x;
  const int lane = tid & 63;
  const int w = tid >> 6;
  #pragma unroll
  for (int r = 0; r < 4; ++r) {
    const int loc = w * 4 + r;
    const int n = b * 16 + loc;
    const int c = T[n];
    uint4 av = *(const uint4*)(Amat + (size_t)n * K_DIM + lane * 16);
    uint4 bv = *(const uint4*)(Bmat + (size_t)c * K_DIM + lane * 16);
    const unsigned char* ab = (const unsigned char*)&av;
    const unsigned char* bb = (const unsigned char*)&bv;
    float s = 0.f;
    #pragma unroll
    for (int i = 0; i < 16; ++i) s += e4m3_to_f(ab[i]) * e4m3_to_f(bb[i]);
    #pragma unroll
    for (int o = 32; o; o >>= 1) s += __shfl_xor(s, o);
    if (lane == 0) tgt_s[loc] = s - tvec[c];
  }
  __syncthreads();
  const int loc = tid >> 4;
  const int n = b * 16 + loc;
  const int l4 = tid & 15;
  float4 pm = *(const float4*)(Pm   + (size_t)n * 64 + l4 * 4);
  float4 ps = *(const float4*)(Psum + (size_t)n * 64 + l4 * 4);
  float m = fmaxf(fmaxf(pm.x, pm.y), fmaxf(pm.z, pm.w));
  #pragma unroll
  for (int o = 1; o < 16; o <<= 1) m = fmaxf(m, __shfl_xor(m, o));
  float S = ps.x * __expf(pm.x - m) + ps.y * __expf(pm.y - m)
          + ps.z * __expf(pm.z - m) + ps.w * __expf(pm.w - m);
  #pragma unroll
  for (int o = 1; o < 16; o <<= 1) S += __shfl_xor(S, o);
  float ce = (l4 == 0) ? (m + logf(S) - tgt_s[loc]) : 0.f;
  float kl = (tid < 32) ? klc[b * 32 + tid] : 0.f;
  ce = block_sum256(ce);
  kl = block_sum256(kl);
  if (tid == 0) { cep[b] = ce; klp[b] = kl; }
}

// K5b: final combine (1 block, 256 threads)
__global__ __launch_bounds__(256) void k_fin2(const float* __restrict__ cep,
                                              const float* __restrict__ klp,
                                              float* __restrict__ out) {
  const int tid = threadIdx.x;
  float ce = block_sum256(cep[tid]);
  float kl = block_sum256(klp[tid]);
  if (tid == 0) out[0] = ce / (float)N_ROWS + 0.2f * (kl / (float)N_CLS);
}

extern "C" void kernel_launch(void* const* d_in, const int* in_sizes, int n_in,
                              void* d_out, int out_size, void* d_ws, size_t ws_size,
                              hipStream_t stream) {
  const float* X          = (const float*)d_in[0];
  // d_in[1] = indices (unused by the reference loss)
  const int*   T          = (const int*)d_in[2];
  const float* proxies    = (const float*)d_in[3];
  const float* sigmas_inv = (const float*)d_in[4];

  char* ws = (char*)d_ws;
  unsigned char* Amat = (unsigned char*)ws;                            // 4 MiB
  unsigned char* Bmat = (unsigned char*)(ws + (4u << 20));             // 8 MiB
  float* tvec = (float*)(ws + (12u << 20));                            // 32 KiB
  float* klc  = (float*)(ws + (12u << 20) + (32u << 10));              // 32 KiB
  float* Pm   = (float*)(ws + (12u << 20) + (64u << 10));              // 1 MiB
  float* Psum = (float*)(ws + (13u << 20) + (64u << 10));              // 1 MiB
  float* cep  = (float*)(ws + (14u << 20) + (64u << 10));              // 1 KiB
  float* klp  = (float*)(ws + (14u << 20) + (68u << 10));              // 1 KiB
  float* out  = (float*)d_out;

  hipLaunchKernelGGL(k_prep,     dim3(N_CLS + N_ROWS), dim3(256), 0, stream,
                     proxies, sigmas_inv, X, Bmat, Amat, tvec, klc);
  hipLaunchKernelGGL(k_gemm_lse, dim3(1024),           dim3(512), 0, stream,
                     Amat, Bmat, tvec, Pm, Psum);
  hipLaunchKernelGGL(k_red,      dim3(256),            dim3(256), 0, stream,
                     Pm, Psum, Amat, Bmat, tvec, T, klc, cep, klp);
  hipLaunchKernelGGL(k_fin2,     dim3(1),              dim3(256), 0, stream,
                     cep, klp, out);
}

// Round 9
// 381.115 us; speedup vs baseline: 1.0027x; 1.0027x over previous
//
#include <hip/hip_runtime.h>
#include <hip/hip_bf16.h>
#include <cstdint>

#define N_ROWS 4096
#define N_CLS  8192
#define D_EMB  512
#define K_DIM  1024   // bytes per row: [x^2 s-channel 512][2x ps-channel 512]

using f32x4  = __attribute__((ext_vector_type(4)))  float;
using f32x16 = __attribute__((ext_vector_type(16))) float;
using i32x4  = __attribute__((ext_vector_type(4)))  int;
using i32x8  = __attribute__((ext_vector_type(8)))  int;

__device__ __forceinline__ float softplus_f(float v) {
  return (v > 20.f) ? v : log1pf(expf(v));
}

// pack 2 f32 -> 2 fp8 e4m3 (OCP, RNE) in low 16 bits
__device__ __forceinline__ unsigned short pack2_e4m3(float a, float b) {
  return (unsigned short)(__builtin_amdgcn_cvt_pk_fp8_f32(a, b, 0, false) & 0xffff);
}

__device__ __forceinline__ float e4m3_to_f(unsigned char v) {
  int e = (v >> 3) & 15, m = v & 7;
  float f;
  if (e) f = __uint_as_float((unsigned int)((e + 120) << 23) | ((unsigned int)m << 20));
  else   f = (float)m * 0.001953125f;   // m * 2^-9
  return (v & 0x80) ? -f : f;
}

// block-wide sum for 256 threads (4 waves); re-entrant (syncs guard the LDS)
__device__ __forceinline__ float block_sum256(float v) {
  __shared__ float red[4];
  #pragma unroll
  for (int o = 32; o; o >>= 1) v += __shfl_xor(v, o);
  __syncthreads();
  if ((threadIdx.x & 63) == 0) red[threadIdx.x >> 6] = v;
  __syncthreads();
  return red[0] + red[1] + red[2] + red[3];
}

__device__ __forceinline__ void global_to_lds16(const void* g, void* l) {
  const __attribute__((address_space(1))) unsigned int* gp =
      reinterpret_cast<const __attribute__((address_space(1))) unsigned int*>(
          reinterpret_cast<uintptr_t>(g));
  __attribute__((address_space(3))) unsigned int* lp =
      reinterpret_cast<__attribute__((address_space(3))) unsigned int*>(
          reinterpret_cast<uintptr_t>(l));
  __builtin_amdgcn_global_load_lds(gp, lp, 16, 0, 0);
}

// ---------------------------------------------------------------------------
// K1: fused prep. Blocks [0, N_CLS): per-class -> Bmat fp8 [s | P*s], tvec,
//     klc. Blocks [N_CLS, N_CLS+N_ROWS): per-row -> Amat fp8 [-Xn^2 | 2Xn].
// ---------------------------------------------------------------------------
__global__ __launch_bounds__(256) void k_prep(const float* __restrict__ proxies,
                                              const float* __restrict__ sigmas_inv,
                                              const float* __restrict__ X,
                                              unsigned char* __restrict__ Bmat,
                                              unsigned char* __restrict__ Amat,
                                              float* __restrict__ tvec,
                                              float* __restrict__ klc) {
  const int bid = blockIdx.x;
  const int tid = threadIdx.x;
  if (bid < N_CLS) {
    const int c = bid;
    const float* p  = proxies    + (size_t)c * D_EMB;
    const float* si = sigmas_inv + (size_t)c * D_EMB;
    float2 p2 = ((const float2*)p)[tid];
    float ss = block_sum256(p2.x * p2.x + p2.y * p2.y);
    float invn = 1.0f / fmaxf(sqrtf(ss), 1e-12f);
    float2 s2 = ((const float2*)si)[tid];
    float sp0 = softplus_f(s2.x), sp1 = softplus_f(s2.y);
    float s0 = sp0 * sp0, s1 = sp1 * sp1;
    float pn0 = p2.x * invn, pn1 = p2.y * invn;
    float P0 = 3.0f * pn0, P1 = 3.0f * pn1;
    unsigned short* brow = (unsigned short*)(Bmat + (size_t)c * K_DIM);
    brow[tid]       = pack2_e4m3(s0, s1);
    brow[256 + tid] = pack2_e4m3(P0 * s0, P1 * s1);
    float tc = P0 * P0 * s0 + P1 * P1 * s1;
    float kl = 0.5f * (1.0f / s0 + pn0 * pn0 - 1.0f + 2.0f * logf(sp0))
             + 0.5f * (1.0f / s1 + pn1 * pn1 - 1.0f + 2.0f * logf(sp1));
    tc = block_sum256(tc);
    kl = block_sum256(kl);
    if (tid == 0) { tvec[c] = tc; klc[c] = kl; }
  } else {
    const int n = bid - N_CLS;
    const float* x = X + (size_t)n * D_EMB;
    float2 x2 = ((const float2*)x)[tid];
    float ss = block_sum256(x2.x * x2.x + x2.y * x2.y);
    float invn = 3.0f / fmaxf(sqrtf(ss), 1e-12f);   // SCALE folded in
    float v0 = x2.x * invn, v1 = x2.y * invn;
    unsigned short* arow = (unsigned short*)(Amat + (size_t)n * K_DIM);
    arow[tid]       = pack2_e4m3(-v0 * v0, -v1 * v1);
    arow[256 + tid] = pack2_e4m3(2.0f * v0, 2.0f * v1);
  }
}

// ---------------------------------------------------------------------------
// K3: 256x128-tile MX-fp8 GEMM, mfma_scale_f32_32x32x64_f8f6f4 with unit
//     scales (== plain fp8 e4m3 dot at 2x MFMA rate; operand layout verified
//     in R8). STAGING = R5-proven: row-major [rows][64B] LDS tiles, XOR
//     involution applied within each row's 64B (source stays coalesced —
//     R8's cross-row scatter was the 6x regression). Fragment read: lane l
//     needs row frag*32+(l&31), bytes (l>>5)*32..+31 -> two ds_read_b128 at
//     swz(L) and swz(L)^16. 8 waves (4M x 2N, 64x64/wave), BK=64, 2-slot
//     LDS (48 KB), stage-then-compute. Fused row max/sumexp epilogue.
// ---------------------------------------------------------------------------
__global__ __launch_bounds__(512, 4) void k_gemm_lse(const unsigned char* __restrict__ Amat,
                                                     const unsigned char* __restrict__ Bmat,
                                                     const float* __restrict__ tvec,
                                                     float* __restrict__ Pm,
                                                     float* __restrict__ Psum) {
  // slot s (24576 B): As[256][64] at s*24576 ; Bs[128][64] at s*24576+16384.
  // Epilogue ms[256][2][2] (4 KB) overlays slot 0; last compute reads slot 1.
  __shared__ __align__(16) unsigned char lds[49152];
  const int tid  = threadIdx.x;
  const int lane = tid & 63;
  const int wave = tid >> 6;
  const int wr = wave >> 1, wc = wave & 1;          // 4x2 wave grid; 64x64/wave
  // T1: chunked XCD swizzle. nwg=1024, 128 consecutive per XCD; rt fastest.
  const int swz  = ((int)blockIdx.x & 7) * 128 + ((int)blockIdx.x >> 3);
  const int rt   = swz & 15;                        // 16 row tiles (256 rows)
  const int ct   = swz >> 4;                        // 64 col tiles (128 cols)
  const int row0 = rt * 256;
  const int col0 = ct * 128;

  const f32x16 Z = {0.f,0.f,0.f,0.f, 0.f,0.f,0.f,0.f, 0.f,0.f,0.f,0.f, 0.f,0.f,0.f,0.f};
  f32x16 acc00 = Z, acc01 = Z, acc10 = Z, acc11 = Z;

  // ---- staging (R5 pattern): linear LDS dest, within-row-permuted source ----
  const int f0  = tid * 16;          // A bytes [0, 8192)
  const int f1  = 8192 + tid * 16;   // A bytes [8192, 16384)
  const int sf0 = f0 ^ (((f0 >> 7) & 7) << 4);
  const int sf1 = f1 ^ (((f1 >> 7) & 7) << 4);
  const unsigned char* gA0 = Amat + (size_t)(row0 + (sf0 >> 6)) * K_DIM + (sf0 & 63);
  const unsigned char* gA1 = Amat + (size_t)(row0 + (sf1 >> 6)) * K_DIM + (sf1 & 63);
  const unsigned char* gB0 = Bmat + (size_t)(col0 + (sf0 >> 6)) * K_DIM + (sf0 & 63);

  auto stg = [&](int slot, int ko) {                // 3 x 16B loads / thread
    unsigned char* base = lds + slot * 24576;
    global_to_lds16(gA0 + ko, base + f0);
    global_to_lds16(gA1 + ko, base + f1);
    global_to_lds16(gB0 + ko, base + 16384 + f0);
  };

  // ---- fragment read offsets (constant per thread; pair = off and off^16) --
  auto swzf = [](int f) { return f ^ (((f >> 7) & 7) << 4); };
  const int koff = (lane >> 5) * 32;
  const int offA0 = swzf((0 * 32 + (lane & 31)) * 64 + koff) + (wr * 64) * 64;   // wr*64 rows = 4096B, bit12+: swizzle key uses bits 7-9 only -> additive above bit 9? NO: fold wr into row BEFORE swizzle
  // (the line above is wrong in general; compute all four properly:)
  const int offA_0 = swzf((wr * 64 + 0  + (lane & 31)) * 64 + koff);
  const int offA_1 = swzf((wr * 64 + 32 + (lane & 31)) * 64 + koff);
  const int offB_0 = 16384 + swzf((wc * 64 + 0  + (lane & 31)) * 64 + koff);
  const int offB_1 = 16384 + swzf((wc * 64 + 32 + (lane & 31)) * 64 + koff);
  (void)offA0;

  auto ldfrag = [&](const unsigned char* S, int off) -> i32x8 {
    i32x4 lo = *(const i32x4*)(S + off);
    i32x4 hi = *(const i32x4*)(S + (off ^ 16));
    return (i32x8){lo[0], lo[1], lo[2], lo[3], hi[0], hi[1], hi[2], hi[3]};
  };

  stg(0, 0);
  __syncthreads();
  for (int t = 0; t < 16; ++t) {
    if (t < 15) stg((t + 1) & 1, (t + 1) * 64);     // issue next-tile loads FIRST
    const unsigned char* S = lds + (t & 1) * 24576;
    i32x8 a0 = ldfrag(S, offA_0);
    i32x8 a1 = ldfrag(S, offA_1);
    i32x8 b0 = ldfrag(S, offB_0);
    i32x8 b1 = ldfrag(S, offB_1);
    __builtin_amdgcn_s_setprio(1);
    acc00 = __builtin_amdgcn_mfma_scale_f32_32x32x64_f8f6f4(a0, b0, acc00, 0, 0, 0, 0x7f7f7f7f, 0, 0x7f7f7f7f);
    acc01 = __builtin_amdgcn_mfma_scale_f32_32x32x64_f8f6f4(a0, b1, acc01, 0, 0, 0, 0x7f7f7f7f, 0, 0x7f7f7f7f);
    acc10 = __builtin_amdgcn_mfma_scale_f32_32x32x64_f8f6f4(a1, b0, acc10, 0, 0, 0, 0x7f7f7f7f, 0, 0x7f7f7f7f);
    acc11 = __builtin_amdgcn_mfma_scale_f32_32x32x64_f8f6f4(a1, b1, acc11, 0, 0, 0, 0x7f7f7f7f, 0, 0x7f7f7f7f);
    __builtin_amdgcn_s_setprio(0);
    __syncthreads();   // drains staging vmcnt AFTER compute: latency hidden
  }

  // ---- epilogue: per-row max / sumexp over this wave's 64 cols.
  // 32x32 C/D layout (verified R8): col = lane&31,
  // row = (r&3) + 8*(r>>2) + 4*(lane>>5).
  float (*ms)[2][2] = (float (*)[2][2])lds;   // overlays slot 0; slot 1 was last read
  const float tc0 = tvec[col0 + wc * 64 + (lane & 31)];
  const float tc1 = tvec[col0 + wc * 64 + 32 + (lane & 31)];
  const int rbase = (lane >> 5) * 4;

  #pragma unroll
  for (int tm = 0; tm < 2; ++tm) {
    const f32x16& CA = tm ? acc10 : acc00;
    const f32x16& CB = tm ? acc11 : acc01;
    #pragma unroll
    for (int r = 0; r < 16; ++r) {
      float z0 = CA[r] - tc0;
      float z1 = CB[r] - tc1;
      float m = fmaxf(z0, z1);
      #pragma unroll
      for (int o = 1; o < 32; o <<= 1) m = fmaxf(m, __shfl_xor(m, o));
      float s = __expf(z0 - m) + __expf(z1 - m);
      #pragma unroll
      for (int o = 1; o < 32; o <<= 1) s += __shfl_xor(s, o);
      if ((lane & 31) == 0) {
        int rloc = wr * 64 + tm * 32 + (r & 3) + 8 * (r >> 2) + rbase;
        ms[rloc][wc][0] = m;
        ms[rloc][wc][1] = s;
      }
    }
  }
  __syncthreads();
  if (tid < 256) {
    float m0 = ms[tid][0][0], s0 = ms[tid][0][1];
    float m1 = ms[tid][1][0], s1 = ms[tid][1][1];
    float M = fmaxf(m0, m1);
    float S = s0 * __expf(m0 - M) + s1 * __expf(m1 - M);
    Pm  [(size_t)(row0 + tid) * 64 + ct] = M;
    Psum[(size_t)(row0 + tid) * 64 + ct] = S;
  }
}

// ---------------------------------------------------------------------------
// K5a: 256-block reduce, target-dot FUSED. Block b:
//      phase 1: rows [b*16, b*16+16): tgt[n] = A[n]·B[T[n]] - t[T[n]]
//      phase 2: same rows -> LSE over 64 partials -> ce partial;
//               classes [b*32, b*32+32) -> kl partial.
// ---------------------------------------------------------------------------
__global__ __launch_bounds__(256) void k_red(const float* __restrict__ Pm,
                                             const float* __restrict__ Psum,
                                             const unsigned char* __restrict__ Amat,
                                             const unsigned char* __restrict__ Bmat,
                                             const float* __restrict__ tvec,
                                             const int* __restrict__ T,
                                             const float* __restrict__ klc,
                                             float* __restrict__ cep,
                                             float* __restrict__ klp) {
  __shared__ float tgt_s[16];
  const int b = blockIdx.x;
  const int tid = threadIdx.x;
  const int lane = tid & 63;
  const int w = tid >> 6;
  #pragma unroll
  for (int r = 0; r < 4; ++r) {
    const int loc = w * 4 + r;
    const int n = b * 16 + loc;
    const int c = T[n];
    uint4 av = *(const uint4*)(Amat + (size_t)n * K_DIM + lane * 16);
    uint4 bv = *(const uint4*)(Bmat + (size_t)c * K_DIM + lane * 16);
    const unsigned char* ab = (const unsigned char*)&av;
    const unsigned char* bb = (const unsigned char*)&bv;
    float s = 0.f;
    #pragma unroll
    for (int i = 0; i < 16; ++i) s += e4m3_to_f(ab[i]) * e4m3_to_f(bb[i]);
    #pragma unroll
    for (int o = 32; o; o >>= 1) s += __shfl_xor(s, o);
    if (lane == 0) tgt_s[loc] = s - tvec[c];
  }
  __syncthreads();
  const int loc = tid >> 4;
  const int n = b * 16 + loc;
  const int l4 = tid & 15;
  float4 pm = *(const float4*)(Pm   + (size_t)n * 64 + l4 * 4);
  float4 ps = *(const float4*)(Psum + (size_t)n * 64 + l4 * 4);
  float m = fmaxf(fmaxf(pm.x, pm.y), fmaxf(pm.z, pm.w));
  #pragma unroll
  for (int o = 1; o < 16; o <<= 1) m = fmaxf(m, __shfl_xor(m, o));
  float S = ps.x * __expf(pm.x - m) + ps.y * __expf(pm.y - m)
          + ps.z * __expf(pm.z - m) + ps.w * __expf(pm.w - m);
  #pragma unroll
  for (int o = 1; o < 16; o <<= 1) S += __shfl_xor(S, o);
  float ce = (l4 == 0) ? (m + logf(S) - tgt_s[loc]) : 0.f;
  float kl = (tid < 32) ? klc[b * 32 + tid] : 0.f;
  ce = block_sum256(ce);
  kl = block_sum256(kl);
  if (tid == 0) { cep[b] = ce; klp[b] = kl; }
}

// K5b: final combine (1 block, 256 threads)
__global__ __launch_bounds__(256) void k_fin2(const float* __restrict__ cep,
                                              const float* __restrict__ klp,
                                              float* __restrict__ out) {
  const int tid = threadIdx.x;
  float ce = block_sum256(cep[tid]);
  float kl = block_sum256(klp[tid]);
  if (tid == 0) out[0] = ce / (float)N_ROWS + 0.2f * (kl / (float)N_CLS);
}

extern "C" void kernel_launch(void* const* d_in, const int* in_sizes, int n_in,
                              void* d_out, int out_size, void* d_ws, size_t ws_size,
                              hipStream_t stream) {
  const float* X          = (const float*)d_in[0];
  // d_in[1] = indices (unused by the reference loss)
  const int*   T          = (const int*)d_in[2];
  const float* proxies    = (const float*)d_in[3];
  const float* sigmas_inv = (const float*)d_in[4];

  char* ws = (char*)d_ws;
  unsigned char* Amat = (unsigned char*)ws;                            // 4 MiB
  unsigned char* Bmat = (unsigned char*)(ws + (4u << 20));             // 8 MiB
  float* tvec = (float*)(ws + (12u << 20));                            // 32 KiB
  float* klc  = (float*)(ws + (12u << 20) + (32u << 10));              // 32 KiB
  float* Pm   = (float*)(ws + (12u << 20) + (64u << 10));              // 1 MiB
  float* Psum = (float*)(ws + (13u << 20) + (64u << 10));              // 1 MiB
  float* cep  = (float*)(ws + (14u << 20) + (64u << 10));              // 1 KiB
  float* klp  = (float*)(ws + (14u << 20) + (68u << 10));              // 1 KiB
  float* out  = (float*)d_out;

  hipLaunchKernelGGL(k_prep,     dim3(N_CLS + N_ROWS), dim3(256), 0, stream,
                     proxies, sigmas_inv, X, Bmat, Amat, tvec, klc);
  hipLaunchKernelGGL(k_gemm_lse, dim3(1024),           dim3(512), 0, stream,
                     Amat, Bmat, tvec, Pm, Psum);
  hipLaunchKernelGGL(k_red,      dim3(256),            dim3(256), 0, stream,
                     Pm, Psum, Amat, Bmat, tvec, T, klc, cep, klp);
  hipLaunchKernelGGL(k_fin2,     dim3(1),              dim3(256), 0, stream,
                     cep, klp, out);
}

// Round 10
// 377.541 us; speedup vs baseline: 1.0122x; 1.0095x over previous
//
#include <hip/hip_runtime.h>
#include <hip/hip_bf16.h>
#include <cstdint>

#define N_ROWS 4096
#define N_CLS  8192
#define D_EMB  512
#define K_DIM  1024   // bytes per row: [x^2 s-channel 512][2x ps-channel 512]

using f32x4  = __attribute__((ext_vector_type(4)))  float;
using f32x16 = __attribute__((ext_vector_type(16))) float;
using i32x4  = __attribute__((ext_vector_type(4)))  int;
using i32x8  = __attribute__((ext_vector_type(8)))  int;

__device__ __forceinline__ float softplus_f(float v) {
  return (v > 20.f) ? v : log1pf(expf(v));
}

// pack 2 f32 -> 2 fp8 e4m3 (OCP, RNE) in low 16 bits
__device__ __forceinline__ unsigned short pack2_e4m3(float a, float b) {
  return (unsigned short)(__builtin_amdgcn_cvt_pk_fp8_f32(a, b, 0, false) & 0xffff);
}

__device__ __forceinline__ float e4m3_to_f(unsigned char v) {
  int e = (v >> 3) & 15, m = v & 7;
  float f;
  if (e) f = __uint_as_float((unsigned int)((e + 120) << 23) | ((unsigned int)m << 20));
  else   f = (float)m * 0.001953125f;   // m * 2^-9
  return (v & 0x80) ? -f : f;
}

// block-wide sum for 256 threads (4 waves); re-entrant (syncs guard the LDS)
__device__ __forceinline__ float block_sum256(float v) {
  __shared__ float red[4];
  #pragma unroll
  for (int o = 32; o; o >>= 1) v += __shfl_xor(v, o);
  __syncthreads();
  if ((threadIdx.x & 63) == 0) red[threadIdx.x >> 6] = v;
  __syncthreads();
  return red[0] + red[1] + red[2] + red[3];
}

__device__ __forceinline__ void global_to_lds16(const void* g, void* l) {
  const __attribute__((address_space(1))) unsigned int* gp =
      reinterpret_cast<const __attribute__((address_space(1))) unsigned int*>(
          reinterpret_cast<uintptr_t>(g));
  __attribute__((address_space(3))) unsigned int* lp =
      reinterpret_cast<__attribute__((address_space(3))) unsigned int*>(
          reinterpret_cast<uintptr_t>(l));
  __builtin_amdgcn_global_load_lds(gp, lp, 16, 0, 0);
}

// ---------------------------------------------------------------------------
// K1: fused prep. Blocks [0, N_CLS): per-class -> Bmat fp8 [s | P*s], tvec,
//     klc. Blocks [N_CLS, N_CLS+N_ROWS): per-row -> Amat fp8 [-Xn^2 | 2Xn].
// ---------------------------------------------------------------------------
__global__ __launch_bounds__(256) void k_prep(const float* __restrict__ proxies,
                                              const float* __restrict__ sigmas_inv,
                                              const float* __restrict__ X,
                                              unsigned char* __restrict__ Bmat,
                                              unsigned char* __restrict__ Amat,
                                              float* __restrict__ tvec,
                                              float* __restrict__ klc) {
  const int bid = blockIdx.x;
  const int tid = threadIdx.x;
  if (bid < N_CLS) {
    const int c = bid;
    const float* p  = proxies    + (size_t)c * D_EMB;
    const float* si = sigmas_inv + (size_t)c * D_EMB;
    float2 p2 = ((const float2*)p)[tid];
    float ss = block_sum256(p2.x * p2.x + p2.y * p2.y);
    float invn = 1.0f / fmaxf(sqrtf(ss), 1e-12f);
    float2 s2 = ((const float2*)si)[tid];
    float sp0 = softplus_f(s2.x), sp1 = softplus_f(s2.y);
    float s0 = sp0 * sp0, s1 = sp1 * sp1;
    float pn0 = p2.x * invn, pn1 = p2.y * invn;
    float P0 = 3.0f * pn0, P1 = 3.0f * pn1;
    unsigned short* brow = (unsigned short*)(Bmat + (size_t)c * K_DIM);
    brow[tid]       = pack2_e4m3(s0, s1);
    brow[256 + tid] = pack2_e4m3(P0 * s0, P1 * s1);
    float tc = P0 * P0 * s0 + P1 * P1 * s1;
    float kl = 0.5f * (1.0f / s0 + pn0 * pn0 - 1.0f + 2.0f * logf(sp0))
             + 0.5f * (1.0f / s1 + pn1 * pn1 - 1.0f + 2.0f * logf(sp1));
    tc = block_sum256(tc);
    kl = block_sum256(kl);
    if (tid == 0) { tvec[c] = tc; klc[c] = kl; }
  } else {
    const int n = bid - N_CLS;
    const float* x = X + (size_t)n * D_EMB;
    float2 x2 = ((const float2*)x)[tid];
    float ss = block_sum256(x2.x * x2.x + x2.y * x2.y);
    float invn = 3.0f / fmaxf(sqrtf(ss), 1e-12f);   // SCALE folded in
    float v0 = x2.x * invn, v1 = x2.y * invn;
    unsigned short* arow = (unsigned short*)(Amat + (size_t)n * K_DIM);
    arow[tid]       = pack2_e4m3(-v0 * v0, -v1 * v1);
    arow[256 + tid] = pack2_e4m3(2.0f * v0, 2.0f * v1);
  }
}

// ---------------------------------------------------------------------------
// K3: 256x128-tile MX-fp8 GEMM, mfma_scale_f32_32x32x64_f8f6f4, unit scales
//     (numerics verified R8/R9). REGISTER-SLIMMED vs R9 (whose 350us was
//     scratch spill, NOT staging: WRITE_SIZE 686MB with only 2MB of real
//     writes): only ONE B operand live at a time (24 operand VGPRs, not 32),
//     staging pointers advanced in-place, all LDS offsets precomputed.
//     Arch-VGPR demand ~50 < 64 available beside 64 AGPR acc at (512,4).
//     8 waves (4M x 2N, 64x64/wave), BK=64, 2-slot LDS, stage-then-compute.
// ---------------------------------------------------------------------------
__global__ __launch_bounds__(512, 4) void k_gemm_lse(const unsigned char* __restrict__ Amat,
                                                     const unsigned char* __restrict__ Bmat,
                                                     const float* __restrict__ tvec,
                                                     float* __restrict__ Pm,
                                                     float* __restrict__ Psum) {
  // slot s (24576 B): As[256][64] at s*24576 ; Bs[128][64] at s*24576+16384.
  // Epilogue ms[256][2][2] (4 KB) overlays slot 0; last compute reads slot 1.
  __shared__ __align__(16) unsigned char lds[49152];
  const int tid  = threadIdx.x;
  const int lane = tid & 63;
  const int wave = tid >> 6;
  const int wr = wave >> 1, wc = wave & 1;          // 4x2 wave grid; 64x64/wave
  // T1: chunked XCD swizzle. nwg=1024, 128 consecutive per XCD; rt fastest.
  const int swz  = ((int)blockIdx.x & 7) * 128 + ((int)blockIdx.x >> 3);
  const int rt   = swz & 15;                        // 16 row tiles (256 rows)
  const int ct   = swz >> 4;                        // 64 col tiles (128 cols)
  const int row0 = rt * 256;
  const int col0 = ct * 128;

  const f32x16 Z = {0.f,0.f,0.f,0.f, 0.f,0.f,0.f,0.f, 0.f,0.f,0.f,0.f, 0.f,0.f,0.f,0.f};
  f32x16 acc00 = Z, acc01 = Z, acc10 = Z, acc11 = Z;

  // ---- staging (R5 pattern): linear LDS dest, within-row-permuted source ---
  const int f0  = tid * 16;          // A bytes [0, 8192)
  const int sf0 = f0 ^ (((f0 >> 7) & 7) << 4);
  // sf(f0+8192) == sf0+8192 (the +0x2000 doesn't touch key bits 7-9), so the
  // second A-load source is a constant 128-row offset from the first.
  const unsigned char* gA0 = Amat + (size_t)(row0 + (sf0 >> 6)) * K_DIM + (sf0 & 63);
  const unsigned char* gB0 = Bmat + (size_t)(col0 + (sf0 >> 6)) * K_DIM + (sf0 & 63);

  auto stg = [&](int slot) {                        // 3 x 16B loads / thread
    unsigned char* base = lds + slot * 24576;
    global_to_lds16(gA0,          base + f0);
    global_to_lds16(gA0 + 131072, base + 8192 + f0);   // +128 rows * 1024 B
    global_to_lds16(gB0,          base + 16384 + f0);
    gA0 += 64; gB0 += 64;                           // advance to next K-tile
  };

  // ---- fragment read offsets (constants per thread) -----------------------
  auto swzf = [](int f) { return f ^ (((f >> 7) & 7) << 4); };
  const int koff = (lane >> 5) * 32;
  const int offA_0 = swzf((wr * 64 + 0  + (lane & 31)) * 64 + koff);
  const int offA_1 = swzf((wr * 64 + 32 + (lane & 31)) * 64 + koff);
  const int offB_0 = 16384 + swzf((wc * 64 + 0  + (lane & 31)) * 64 + koff);
  const int offB_1 = 16384 + swzf((wc * 64 + 32 + (lane & 31)) * 64 + koff);

  auto ldfrag = [&](const unsigned char* S, int off) -> i32x8 {
    i32x4 lo = *(const i32x4*)(S + off);
    i32x4 hi = *(const i32x4*)(S + (off ^ 16));
    return (i32x8){lo[0], lo[1], lo[2], lo[3], hi[0], hi[1], hi[2], hi[3]};
  };

  stg(0);
  __syncthreads();
  for (int t = 0; t < 16; ++t) {
    if (t < 15) stg((t + 1) & 1);                   // issue next-tile loads FIRST
    const unsigned char* S = lds + (t & 1) * 24576;
    i32x8 a0 = ldfrag(S, offA_0);
    i32x8 a1 = ldfrag(S, offA_1);
    i32x8 b  = ldfrag(S, offB_0);
    __builtin_amdgcn_s_setprio(1);
    acc00 = __builtin_amdgcn_mfma_scale_f32_32x32x64_f8f6f4(a0, b, acc00, 0, 0, 0, 0x7f7f7f7f, 0, 0x7f7f7f7f);
    acc10 = __builtin_amdgcn_mfma_scale_f32_32x32x64_f8f6f4(a1, b, acc10, 0, 0, 0, 0x7f7f7f7f, 0, 0x7f7f7f7f);
    b = ldfrag(S, offB_1);
    acc01 = __builtin_amdgcn_mfma_scale_f32_32x32x64_f8f6f4(a0, b, acc01, 0, 0, 0, 0x7f7f7f7f, 0, 0x7f7f7f7f);
    acc11 = __builtin_amdgcn_mfma_scale_f32_32x32x64_f8f6f4(a1, b, acc11, 0, 0, 0, 0x7f7f7f7f, 0, 0x7f7f7f7f);
    __builtin_amdgcn_s_setprio(0);
    __syncthreads();   // drains staging vmcnt AFTER compute: latency hidden
  }

  // ---- epilogue: per-row max / sumexp over this wave's 64 cols.
  // 32x32 C/D layout (verified R8/R9): col = lane&31,
  // row = (r&3) + 8*(r>>2) + 4*(lane>>5).
  float (*ms)[2][2] = (float (*)[2][2])lds;   // overlays slot 0; slot 1 was last read
  const float tc0 = tvec[col0 + wc * 64 + (lane & 31)];
  const float tc1 = tvec[col0 + wc * 64 + 32 + (lane & 31)];
  const int rbase = (lane >> 5) * 4;

  #pragma unroll
  for (int tm = 0; tm < 2; ++tm) {
    const f32x16& CA = tm ? acc10 : acc00;
    const f32x16& CB = tm ? acc11 : acc01;
    #pragma unroll
    for (int r = 0; r < 16; ++r) {
      float z0 = CA[r] - tc0;
      float z1 = CB[r] - tc1;
      float m = fmaxf(z0, z1);
      #pragma unroll
      for (int o = 1; o < 32; o <<= 1) m = fmaxf(m, __shfl_xor(m, o));
      float s = __expf(z0 - m) + __expf(z1 - m);
      #pragma unroll
      for (int o = 1; o < 32; o <<= 1) s += __shfl_xor(s, o);
      if ((lane & 31) == 0) {
        int rloc = wr * 64 + tm * 32 + (r & 3) + 8 * (r >> 2) + rbase;
        ms[rloc][wc][0] = m;
        ms[rloc][wc][1] = s;
      }
    }
  }
  __syncthreads();
  if (tid < 256) {
    float m0 = ms[tid][0][0], s0 = ms[tid][0][1];
    float m1 = ms[tid][1][0], s1 = ms[tid][1][1];
    float M = fmaxf(m0, m1);
    float S = s0 * __expf(m0 - M) + s1 * __expf(m1 - M);
    Pm  [(size_t)(row0 + tid) * 64 + ct] = M;
    Psum[(size_t)(row0 + tid) * 64 + ct] = S;
  }
}

// ---------------------------------------------------------------------------
// K5a: 256-block reduce, target-dot FUSED. Block b:
//      phase 1: rows [b*16, b*16+16): tgt[n] = A[n]·B[T[n]] - t[T[n]]
//      phase 2: same rows -> LSE over 64 partials -> ce partial;
//               classes [b*32, b*32+32) -> kl partial.
// ---------------------------------------------------------------------------
__global__ __launch_bounds__(256) void k_red(const float* __restrict__ Pm,
                                             const float* __restrict__ Psum,
                                             const unsigned char* __restrict__ Amat,
                                             const unsigned char* __restrict__ Bmat,
                                             const float* __restrict__ tvec,
                                             const int* __restrict__ T,
                                             const float* __restrict__ klc,
                                             float* __restrict__ cep,
                                             float* __restrict__ klp) {
  __shared__ float tgt_s[16];
  const int b = blockIdx.x;
  const int tid = threadIdx.x;
  const int lane = tid & 63;
  const int w = tid >> 6;
  #pragma unroll
  for (int r = 0; r < 4; ++r) {
    const int loc = w * 4 + r;
    const int n = b * 16 + loc;
    const int c = T[n];
    uint4 av = *(const uint4*)(Amat + (size_t)n * K_DIM + lane * 16);
    uint4 bv = *(const uint4*)(Bmat + (size_t)c * K_DIM + lane * 16);
    const unsigned char* ab = (const unsigned char*)&av;
    const unsigned char* bb = (const unsigned char*)&bv;
    float s = 0.f;
    #pragma unroll
    for (int i = 0; i < 16; ++i) s += e4m3_to_f(ab[i]) * e4m3_to_f(bb[i]);
    #pragma unroll
    for (int o = 32; o; o >>= 1) s += __shfl_xor(s, o);
    if (lane == 0) tgt_s[loc] = s - tvec[c];
  }
  __syncthreads();
  const int loc = tid >> 4;
  const int n = b * 16 + loc;
  const int l4 = tid & 15;
  float4 pm = *(const float4*)(Pm   + (size_t)n * 64 + l4 * 4);
  float4 ps = *(const float4*)(Psum + (size_t)n * 64 + l4 * 4);
  float m = fmaxf(fmaxf(pm.x, pm.y), fmaxf(pm.z, pm.w));
  #pragma unroll
  for (int o = 1; o < 16; o <<= 1) m = fmaxf(m, __shfl_xor(m, o));
  float S = ps.x * __expf(pm.x - m) + ps.y * __expf(pm.y - m)
          + ps.z * __expf(pm.z - m) + ps.w * __expf(pm.w - m);
  #pragma unroll
  for (int o = 1; o < 16; o <<= 1) S += __shfl_xor(S, o);
  float ce = (l4 == 0) ? (m + logf(S) - tgt_s[loc]) : 0.f;
  float kl = (tid < 32) ? klc[b * 32 + tid] : 0.f;
  ce = block_sum256(ce);
  kl = block_sum256(kl);
  if (tid == 0) { cep[b] = ce; klp[b] = kl; }
}

// K5b: final combine (1 block, 256 threads)
__global__ __launch_bounds__(256) void k_fin2(const float* __restrict__ cep,
                                              const float* __restrict__ klp,
                                              float* __restrict__ out) {
  const int tid = threadIdx.x;
  float ce = block_sum256(cep[tid]);
  float kl = block_sum256(klp[tid]);
  if (tid == 0) out[0] = ce / (float)N_ROWS + 0.2f * (kl / (float)N_CLS);
}

extern "C" void kernel_launch(void* const* d_in, const int* in_sizes, int n_in,
                              void* d_out, int out_size, void* d_ws, size_t ws_size,
                              hipStream_t stream) {
  const float* X          = (const float*)d_in[0];
  // d_in[1] = indices (unused by the reference loss)
  const int*   T          = (const int*)d_in[2];
  const float* proxies    = (const float*)d_in[3];
  const float* sigmas_inv = (const float*)d_in[4];

  char* ws = (char*)d_ws;
  unsigned char* Amat = (unsigned char*)ws;                            // 4 MiB
  unsigned char* Bmat = (unsigned char*)(ws + (4u << 20));             // 8 MiB
  float* tvec = (float*)(ws + (12u << 20));                            // 32 KiB
  float* klc  = (float*)(ws + (12u << 20) + (32u << 10));              // 32 KiB
  float* Pm   = (float*)(ws + (12u << 20) + (64u << 10));              // 1 MiB
  float* Psum = (float*)(ws + (13u << 20) + (64u << 10));              // 1 MiB
  float* cep  = (float*)(ws + (14u << 20) + (64u << 10));              // 1 KiB
  float* klp  = (float*)(ws + (14u << 20) + (68u << 10));              // 1 KiB
  float* out  = (float*)d_out;

  hipLaunchKernelGGL(k_prep,     dim3(N_CLS + N_ROWS), dim3(256), 0, stream,
                     proxies, sigmas_inv, X, Bmat, Amat, tvec, klc);
  hipLaunchKernelGGL(k_gemm_lse, dim3(1024),           dim3(512), 0, stream,
                     Amat, Bmat, tvec, Pm, Psum);
  hipLaunchKernelGGL(k_red,      dim3(256),            dim3(256), 0, stream,
                     Pm, Psum, Amat, Bmat, tvec, T, klc, cep, klp);
  hipLaunchKernelGGL(k_fin2,     dim3(1),              dim3(256), 0, stream,
                     cep, klp, out);
}

// Round 11
// 112.298 us; speedup vs baseline: 3.4029x; 3.3620x over previous
//
#include <hip/hip_runtime.h>
#include <hip/hip_bf16.h>
#include <cstdint>

#define N_ROWS 4096
#define N_CLS  8192
#define D_EMB  512
#define K_DIM  1024   // bytes per row: [x^2 s-channel 512][2x ps-channel 512]

using f32x4 = __attribute__((ext_vector_type(4))) float;

__device__ __forceinline__ float softplus_f(float v) {
  return (v > 20.f) ? v : log1pf(expf(v));
}

// pack 2 f32 -> 2 fp8 e4m3 (OCP, RNE) in low 16 bits
__device__ __forceinline__ unsigned short pack2_e4m3(float a, float b) {
  return (unsigned short)(__builtin_amdgcn_cvt_pk_fp8_f32(a, b, 0, false) & 0xffff);
}

__device__ __forceinline__ float e4m3_to_f(unsigned char v) {
  int e = (v >> 3) & 15, m = v & 7;
  float f;
  if (e) f = __uint_as_float((unsigned int)((e + 120) << 23) | ((unsigned int)m << 20));
  else   f = (float)m * 0.001953125f;   // m * 2^-9
  return (v & 0x80) ? -f : f;
}

// block-wide sum for 256 threads (4 waves); re-entrant (syncs guard the LDS)
__device__ __forceinline__ float block_sum256(float v) {
  __shared__ float red[4];
  #pragma unroll
  for (int o = 32; o; o >>= 1) v += __shfl_xor(v, o);
  __syncthreads();
  if ((threadIdx.x & 63) == 0) red[threadIdx.x >> 6] = v;
  __syncthreads();
  return red[0] + red[1] + red[2] + red[3];
}

__device__ __forceinline__ void global_to_lds16(const void* g, void* l) {
  const __attribute__((address_space(1))) unsigned int* gp =
      reinterpret_cast<const __attribute__((address_space(1))) unsigned int*>(
          reinterpret_cast<uintptr_t>(g));
  __attribute__((address_space(3))) unsigned int* lp =
      reinterpret_cast<__attribute__((address_space(3))) unsigned int*>(
          reinterpret_cast<uintptr_t>(l));
  __builtin_amdgcn_global_load_lds(gp, lp, 16, 0, 0);
}

// ---------------------------------------------------------------------------
// K1: fused prep. Blocks [0, N_CLS): per-class -> Bmat fp8 [s | P*s], tvec,
//     klc. Blocks [N_CLS, N_CLS+N_ROWS): per-row -> Amat fp8 [-Xn^2 | 2Xn].
// ---------------------------------------------------------------------------
__global__ __launch_bounds__(256) void k_prep(const float* __restrict__ proxies,
                                              const float* __restrict__ sigmas_inv,
                                              const float* __restrict__ X,
                                              unsigned char* __restrict__ Bmat,
                                              unsigned char* __restrict__ Amat,
                                              float* __restrict__ tvec,
                                              float* __restrict__ klc) {
  const int bid = blockIdx.x;
  const int tid = threadIdx.x;
  if (bid < N_CLS) {
    const int c = bid;
    const float* p  = proxies    + (size_t)c * D_EMB;
    const float* si = sigmas_inv + (size_t)c * D_EMB;
    float2 p2 = ((const float2*)p)[tid];
    float ss = block_sum256(p2.x * p2.x + p2.y * p2.y);
    float invn = 1.0f / fmaxf(sqrtf(ss), 1e-12f);
    float2 s2 = ((const float2*)si)[tid];
    float sp0 = softplus_f(s2.x), sp1 = softplus_f(s2.y);
    float s0 = sp0 * sp0, s1 = sp1 * sp1;
    float pn0 = p2.x * invn, pn1 = p2.y * invn;
    float P0 = 3.0f * pn0, P1 = 3.0f * pn1;
    unsigned short* brow = (unsigned short*)(Bmat + (size_t)c * K_DIM);
    brow[tid]       = pack2_e4m3(s0, s1);
    brow[256 + tid] = pack2_e4m3(P0 * s0, P1 * s1);
    float tc = P0 * P0 * s0 + P1 * P1 * s1;
    float kl = 0.5f * (1.0f / s0 + pn0 * pn0 - 1.0f + 2.0f * logf(sp0))
             + 0.5f * (1.0f / s1 + pn1 * pn1 - 1.0f + 2.0f * logf(sp1));
    tc = block_sum256(tc);
    kl = block_sum256(kl);
    if (tid == 0) { tvec[c] = tc; klc[c] = kl; }
  } else {
    const int n = bid - N_CLS;
    const float* x = X + (size_t)n * D_EMB;
    float2 x2 = ((const float2*)x)[tid];
    float ss = block_sum256(x2.x * x2.x + x2.y * x2.y);
    float invn = 3.0f / fmaxf(sqrtf(ss), 1e-12f);   // SCALE folded in
    float v0 = x2.x * invn, v1 = x2.y * invn;
    unsigned short* arow = (unsigned short*)(Amat + (size_t)n * K_DIM);
    arow[tid]       = pack2_e4m3(-v0 * v0, -v1 * v1);
    arow[256 + tid] = pack2_e4m3(2.0f * v0, 2.0f * v1);
  }
}

// ---------------------------------------------------------------------------
// K3: 256x256-tile plain-fp8 MFMA GEMM (mfma_f32_16x16x32_fp8_fp8, the
//     R5-proven path). 8 waves (2M x 4N), per-wave 128x64 out (acc=128 regs,
//     spill-free at (512,2) per R3/R4). BK=64, 2-slot LDS (64 KB -> 2
//     blocks/CU = 16 waves/CU). vs R5's 256x128: staging volume/CU -33%,
//     LDS-read/output -25%, half the blocks (half the prologue/barriers).
//     Stage-then-compute pipeline, XOR-involution swizzle (source+read),
//     setprio, XCD chunking. Fused row max/sumexp epilogue -> Pm/Psum[n][32].
// ---------------------------------------------------------------------------
__global__ __launch_bounds__(512, 2) void k_gemm_lse(const unsigned char* __restrict__ Amat,
                                                     const unsigned char* __restrict__ Bmat,
                                                     const float* __restrict__ tvec,
                                                     float* __restrict__ Pm,
                                                     float* __restrict__ Psum) {
  // LDS: As[2][16384] at 0 ; Bs[2][16384] at 32768 ; total 65536 B.
  // Epilogue ms[256][4][2] (8 KB) overlays As[0]; last compute reads slot 1.
  __shared__ __align__(16) unsigned char lds[65536];
  const int tid  = threadIdx.x;
  const int lane = tid & 63;
  const int wave = tid >> 6;
  const int wr = wave >> 2, wc = wave & 3;          // 2x4 wave grid; 128x64/wave
  // T1: chunked XCD swizzle. nwg=512, 64 consecutive per XCD; rt fastest.
  const int swz  = ((int)blockIdx.x & 7) * 64 + ((int)blockIdx.x >> 3);
  const int rt   = swz & 15;                        // 16 row tiles (256 rows)
  const int ct   = swz >> 4;                        // 32 col tiles (256 cols)
  const int row0 = rt * 256;
  const int col0 = ct * 256;

  f32x4 acc[8][4];
  #pragma unroll
  for (int i = 0; i < 8; ++i)
    #pragma unroll
    for (int j = 0; j < 4; ++j) acc[i][j] = (f32x4){0.f, 0.f, 0.f, 0.f};

  // ---- staging (R5 pattern): linear LDS dest, involution-permuted source --
  const int f0  = tid * 16;          // covers bytes [0, 8192) = rows 0..127
  const int sf0 = f0 ^ (((f0 >> 7) & 7) << 4);
  // sf(f0+8192) == sf0+8192 (bit 13 doesn't touch key bits 7-9).
  const unsigned char* gA0 = Amat + (size_t)(row0 + (sf0 >> 6)) * K_DIM + (sf0 & 63);
  const unsigned char* gB0 = Bmat + (size_t)(col0 + (sf0 >> 6)) * K_DIM + (sf0 & 63);

  auto stg = [&](int slot, int ko) {                // 4 x 16B loads / thread
    unsigned char* la = lds + slot * 16384;
    unsigned char* lb = lds + 32768 + slot * 16384;
    global_to_lds16(gA0 + ko,          la + f0);
    global_to_lds16(gA0 + 131072 + ko, la + 8192 + f0);   // rows 128..255
    global_to_lds16(gB0 + ko,          lb + f0);
    global_to_lds16(gB0 + 131072 + ko, lb + 8192 + f0);
  };

  // ---- fragment read offsets (constants; static-indexed arrays) -----------
  auto swzf = [](int f) { return f ^ (((f >> 7) & 7) << 4); };
  const int l15 = lane & 15;
  const int kb8 = (lane >> 4) * 8;
  int offA[8][2], offB[4][2];
  #pragma unroll
  for (int mi = 0; mi < 8; ++mi)
    #pragma unroll
    for (int s = 0; s < 2; ++s)
      offA[mi][s] = swzf((wr * 128 + mi * 16 + l15) * 64 + s * 32 + kb8);
  #pragma unroll
  for (int ni = 0; ni < 4; ++ni)
    #pragma unroll
    for (int s = 0; s < 2; ++s)
      offB[ni][s] = 32768 + swzf((wc * 64 + ni * 16 + l15) * 64 + s * 32 + kb8);

  stg(0, 0);
  __syncthreads();
  for (int t = 0; t < 16; ++t) {
    if (t < 15) stg((t + 1) & 1, (t + 1) * 64);     // issue next-tile loads FIRST
    const unsigned char* S = lds + (t & 1) * 16384;
    __builtin_amdgcn_s_setprio(1);
    #pragma unroll
    for (int s = 0; s < 2; ++s) {
      long a[8], b[4];
      #pragma unroll
      for (int mi = 0; mi < 8; ++mi) a[mi] = *(const long*)(S + offA[mi][s]);
      #pragma unroll
      for (int ni = 0; ni < 4; ++ni) b[ni] = *(const long*)(S + offB[ni][s]);
      #pragma unroll
      for (int mi = 0; mi < 8; ++mi)
        #pragma unroll
        for (int ni = 0; ni < 4; ++ni)
          acc[mi][ni] = __builtin_amdgcn_mfma_f32_16x16x32_fp8_fp8(a[mi], b[ni], acc[mi][ni], 0, 0, 0);
    }
    __builtin_amdgcn_s_setprio(0);
    __syncthreads();   // drains staging vmcnt AFTER compute: latency hidden
  }

  // ---- in-register epilogue: per-row max / sumexp over this wave's 64 cols.
  // C/D layout: col = lane&15, row = (lane>>4)*4 + j.
  float (*ms)[4][2] = (float (*)[4][2])lds;   // overlays As[0]; slot 1 was last read
  float tc[4];
  #pragma unroll
  for (int ni = 0; ni < 4; ++ni)
    tc[ni] = tvec[col0 + wc * 64 + ni * 16 + l15];

  #pragma unroll
  for (int mi = 0; mi < 8; ++mi) {
    #pragma unroll
    for (int j = 0; j < 4; ++j) {
      float z0 = acc[mi][0][j] - tc[0];
      float z1 = acc[mi][1][j] - tc[1];
      float z2 = acc[mi][2][j] - tc[2];
      float z3 = acc[mi][3][j] - tc[3];
      float m = fmaxf(fmaxf(z0, z1), fmaxf(z2, z3));
      #pragma unroll
      for (int o = 1; o < 16; o <<= 1) m = fmaxf(m, __shfl_xor(m, o));
      float s = __expf(z0 - m) + __expf(z1 - m) + __expf(z2 - m) + __expf(z3 - m);
      #pragma unroll
      for (int o = 1; o < 16; o <<= 1) s += __shfl_xor(s, o);
      if (l15 == 0) {
        int rloc = wr * 128 + mi * 16 + ((lane >> 4) << 2) + j;
        ms[rloc][wc][0] = m;
        ms[rloc][wc][1] = s;
      }
    }
  }
  __syncthreads();
  if (tid < 256) {
    float m0 = ms[tid][0][0], s0 = ms[tid][0][1];
    float m1 = ms[tid][1][0], s1 = ms[tid][1][1];
    float m2 = ms[tid][2][0], s2 = ms[tid][2][1];
    float m3 = ms[tid][3][0], s3 = ms[tid][3][1];
    float M = fmaxf(fmaxf(m0, m1), fmaxf(m2, m3));
    float S = s0 * __expf(m0 - M) + s1 * __expf(m1 - M)
            + s2 * __expf(m2 - M) + s3 * __expf(m3 - M);
    Pm  [(size_t)(row0 + tid) * 32 + ct] = M;
    Psum[(size_t)(row0 + tid) * 32 + ct] = S;
  }
}

// ---------------------------------------------------------------------------
// K5a: 128-block reduce, target-dot FUSED. Block b:
//      phase 1: rows [b*32, b*32+32): tgt[n] = A[n]·B[T[n]] - t[T[n]]
//               (1 wave per 8 rows, full-wave dot over 1024 fp8)
//      phase 2: same rows -> LSE over 32 partials (8 lanes/row) -> ce;
//               classes [b*64, b*64+64) -> kl partial.
// ---------------------------------------------------------------------------
__global__ __launch_bounds__(256) void k_red(const float* __restrict__ Pm,
                                             const float* __restrict__ Psum,
                                             const unsigned char* __restrict__ Amat,
                                             const unsigned char* __restrict__ Bmat,
                                             const float* __restrict__ tvec,
                                             const int* __restrict__ T,
                                             const float* __restrict__ klc,
                                             float* __restrict__ cep,
                                             float* __restrict__ klp) {
  __shared__ float tgt_s[32];
  const int b = blockIdx.x;
  const int tid = threadIdx.x;
  const int lane = tid & 63;
  const int w = tid >> 6;
  #pragma unroll
  for (int r = 0; r < 8; ++r) {
    const int loc = w * 8 + r;
    const int n = b * 32 + loc;
    const int c = T[n];
    uint4 av = *(const uint4*)(Amat + (size_t)n * K_DIM + lane * 16);
    uint4 bv = *(const uint4*)(Bmat + (size_t)c * K_DIM + lane * 16);
    const unsigned char* ab = (const unsigned char*)&av;
    const unsigned char* bb = (const unsigned char*)&bv;
    float s = 0.f;
    #pragma unroll
    for (int i = 0; i < 16; ++i) s += e4m3_to_f(ab[i]) * e4m3_to_f(bb[i]);
    #pragma unroll
    for (int o = 32; o; o >>= 1) s += __shfl_xor(s, o);
    if (lane == 0) tgt_s[loc] = s - tvec[c];
  }
  __syncthreads();
  // phase 2: 8 lanes/row, one float4 each over the 32 partials
  const int loc = tid >> 3;
  const int n = b * 32 + loc;
  const int l8 = tid & 7;
  float4 pm = *(const float4*)(Pm   + (size_t)n * 32 + l8 * 4);
  float4 ps = *(const float4*)(Psum + (size_t)n * 32 + l8 * 4);
  float m = fmaxf(fmaxf(pm.x, pm.y), fmaxf(pm.z, pm.w));
  #pragma unroll
  for (int o = 1; o < 8; o <<= 1) m = fmaxf(m, __shfl_xor(m, o));
  float S = ps.x * __expf(pm.x - m) + ps.y * __expf(pm.y - m)
          + ps.z * __expf(pm.z - m) + ps.w * __expf(pm.w - m);
  #pragma unroll
  for (int o = 1; o < 8; o <<= 1) S += __shfl_xor(S, o);
  float ce = (l8 == 0) ? (m + logf(S) - tgt_s[loc]) : 0.f;
  float kl = (tid < 64) ? klc[b * 64 + tid] : 0.f;
  ce = block_sum256(ce);
  kl = block_sum256(kl);
  if (tid == 0) { cep[b] = ce; klp[b] = kl; }
}

// K5b: final combine (1 block, 256 threads; 128 partials)
__global__ __launch_bounds__(256) void k_fin2(const float* __restrict__ cep,
                                              const float* __restrict__ klp,
                                              float* __restrict__ out) {
  const int tid = threadIdx.x;
  float ce = block_sum256(tid < 128 ? cep[tid] : 0.f);
  float kl = block_sum256(tid < 128 ? klp[tid] : 0.f);
  if (tid == 0) out[0] = ce / (float)N_ROWS + 0.2f * (kl / (float)N_CLS);
}

extern "C" void kernel_launch(void* const* d_in, const int* in_sizes, int n_in,
                              void* d_out, int out_size, void* d_ws, size_t ws_size,
                              hipStream_t stream) {
  const float* X          = (const float*)d_in[0];
  // d_in[1] = indices (unused by the reference loss)
  const int*   T          = (const int*)d_in[2];
  const float* proxies    = (const float*)d_in[3];
  const float* sigmas_inv = (const float*)d_in[4];

  char* ws = (char*)d_ws;
  unsigned char* Amat = (unsigned char*)ws;                            // 4 MiB
  unsigned char* Bmat = (unsigned char*)(ws + (4u << 20));             // 8 MiB
  float* tvec = (float*)(ws + (12u << 20));                            // 32 KiB
  float* klc  = (float*)(ws + (12u << 20) + (32u << 10));              // 32 KiB
  float* Pm   = (float*)(ws + (12u << 20) + (64u << 10));              // 512 KiB
  float* Psum = (float*)(ws + (12u << 20) + (576u << 10));             // 512 KiB
  float* cep  = (float*)(ws + (12u << 20) + (1088u << 10));            // 512 B
  float* klp  = (float*)(ws + (12u << 20) + (1092u << 10));            // 512 B
  float* out  = (float*)d_out;

  hipLaunchKernelGGL(k_prep,     dim3(N_CLS + N_ROWS), dim3(256), 0, stream,
                     proxies, sigmas_inv, X, Bmat, Amat, tvec, klc);
  hipLaunchKernelGGL(k_gemm_lse, dim3(512),            dim3(512), 0, stream,
                     Amat, Bmat, tvec, Pm, Psum);
  hipLaunchKernelGGL(k_red,      dim3(128),            dim3(256), 0, stream,
                     Pm, Psum, Amat, Bmat, tvec, T, klc, cep, klp);
  hipLaunchKernelGGL(k_fin2,     dim3(1),              dim3(256), 0, stream,
                     cep, klp, out);
}

// Round 12
// 89.081 us; speedup vs baseline: 4.2898x; 1.2606x over previous
//
#include <hip/hip_runtime.h>
#include <hip/hip_bf16.h>
#include <cstdint>

#define N_ROWS 4096
#define N_CLS  8192
#define D_EMB  512
#define K_DIM  1024   // bytes per row: [x^2 s-channel 512][2x ps-channel 512]

using f32x4 = __attribute__((ext_vector_type(4))) float;

__device__ __forceinline__ float softplus_f(float v) {
  return (v > 20.f) ? v : log1pf(expf(v));
}

// pack 2 f32 -> 2 fp8 e4m3 (OCP, RNE) in low 16 bits
__device__ __forceinline__ unsigned short pack2_e4m3(float a, float b) {
  return (unsigned short)(__builtin_amdgcn_cvt_pk_fp8_f32(a, b, 0, false) & 0xffff);
}

// block-wide sum for 256 threads (4 waves); re-entrant (syncs guard the LDS)
__device__ __forceinline__ float block_sum256(float v) {
  __shared__ float red[4];
  #pragma unroll
  for (int o = 32; o; o >>= 1) v += __shfl_xor(v, o);
  __syncthreads();
  if ((threadIdx.x & 63) == 0) red[threadIdx.x >> 6] = v;
  __syncthreads();
  return red[0] + red[1] + red[2] + red[3];
}

__device__ __forceinline__ void global_to_lds16(const void* g, void* l) {
  const __attribute__((address_space(1))) unsigned int* gp =
      reinterpret_cast<const __attribute__((address_space(1))) unsigned int*>(
          reinterpret_cast<uintptr_t>(g));
  __attribute__((address_space(3))) unsigned int* lp =
      reinterpret_cast<__attribute__((address_space(3))) unsigned int*>(
          reinterpret_cast<uintptr_t>(l));
  __builtin_amdgcn_global_load_lds(gp, lp, 16, 0, 0);
}

// ---------------------------------------------------------------------------
// K1: fused prep. Blocks [0, N_CLS): per-class -> Bmat fp8 [s | P*s], tvec,
//     klc. Blocks [N_CLS, N_CLS+N_ROWS): per-row -> Amat fp8 [-Xn^2 | 2Xn].
// ---------------------------------------------------------------------------
__global__ __launch_bounds__(256) void k_prep(const float* __restrict__ proxies,
                                              const float* __restrict__ sigmas_inv,
                                              const float* __restrict__ X,
                                              unsigned char* __restrict__ Bmat,
                                              unsigned char* __restrict__ Amat,
                                              float* __restrict__ tvec,
                                              float* __restrict__ klc) {
  const int bid = blockIdx.x;
  const int tid = threadIdx.x;
  if (bid < N_CLS) {
    const int c = bid;
    const float* p  = proxies    + (size_t)c * D_EMB;
    const float* si = sigmas_inv + (size_t)c * D_EMB;
    float2 p2 = ((const float2*)p)[tid];
    float ss = block_sum256(p2.x * p2.x + p2.y * p2.y);
    float invn = 1.0f / fmaxf(sqrtf(ss), 1e-12f);
    float2 s2 = ((const float2*)si)[tid];
    float sp0 = softplus_f(s2.x), sp1 = softplus_f(s2.y);
    float s0 = sp0 * sp0, s1 = sp1 * sp1;
    float pn0 = p2.x * invn, pn1 = p2.y * invn;
    float P0 = 3.0f * pn0, P1 = 3.0f * pn1;
    unsigned short* brow = (unsigned short*)(Bmat + (size_t)c * K_DIM);
    brow[tid]       = pack2_e4m3(s0, s1);
    brow[256 + tid] = pack2_e4m3(P0 * s0, P1 * s1);
    float tc = P0 * P0 * s0 + P1 * P1 * s1;
    float kl = 0.5f * (1.0f / s0 + pn0 * pn0 - 1.0f + 2.0f * logf(sp0))
             + 0.5f * (1.0f / s1 + pn1 * pn1 - 1.0f + 2.0f * logf(sp1));
    tc = block_sum256(tc);
    kl = block_sum256(kl);
    if (tid == 0) { tvec[c] = tc; klc[c] = kl; }
  } else {
    const int n = bid - N_CLS;
    const float* x = X + (size_t)n * D_EMB;
    float2 x2 = ((const float2*)x)[tid];
    float ss = block_sum256(x2.x * x2.x + x2.y * x2.y);
    float invn = 3.0f / fmaxf(sqrtf(ss), 1e-12f);   // SCALE folded in
    float v0 = x2.x * invn, v1 = x2.y * invn;
    unsigned short* arow = (unsigned short*)(Amat + (size_t)n * K_DIM);
    arow[tid]       = pack2_e4m3(-v0 * v0, -v1 * v1);
    arow[256 + tid] = pack2_e4m3(2.0f * v0, 2.0f * v1);
  }
}

// ---------------------------------------------------------------------------
// K3: R5-verbatim 256x128-tile fp8 MFMA GEMM (61.9us, the measured optimum of
//     the tile scan 128^2/256x128/256^2 and of 4 scheduling variants), plus a
//     fused target-logit extraction in the epilogue: the one thread holding
//     z[n, T[n]] (col match) writes tgt[n]. tgt then carries the SAME MFMA
//     quantization as the LSE logits (errors cancel in ce).
//     8 waves = 4M x 2N, per-wave 64x64 out; BK=64, 2-slot LDS (48 KB),
//     stage-then-compute, XOR-involution swizzle, setprio, XCD chunking.
// ---------------------------------------------------------------------------
__global__ __launch_bounds__(512, 4) void k_gemm_lse(const unsigned char* __restrict__ Amat,
                                                     const unsigned char* __restrict__ Bmat,
                                                     const float* __restrict__ tvec,
                                                     const int* __restrict__ T,
                                                     float* __restrict__ Pm,
                                                     float* __restrict__ Psum,
                                                     float* __restrict__ tgt) {
  union SMem {
    struct { unsigned char As[2][16384]; unsigned char Bs[2][8192]; } st; // 48 KB
    float ms[256][2][2];   // 4 KB epilogue combine (overlays As[0]; last tile reads slot 1)
  };
  __shared__ SMem sm;
  const int tid  = threadIdx.x;
  const int lane = tid & 63;
  const int wave = tid >> 6;
  const int wr = wave >> 1, wc = wave & 1;          // 4x2 wave grid; per-wave 64x64 out
  // T1: chunked XCD swizzle. nwg=1024, 128 consecutive per XCD.
  const int swz  = ((int)blockIdx.x & 7) * 128 + ((int)blockIdx.x >> 3);
  const int rt   = swz & 15;                        // 16 row tiles (256 rows)
  const int ct   = swz >> 4;                        // 64 col tiles (128 cols)
  const int row0 = rt * 256;
  const int col0 = ct * 128;

  f32x4 acc[4][4];
  #pragma unroll
  for (int i = 0; i < 4; ++i)
    #pragma unroll
    for (int j = 0; j < 4; ++j) acc[i][j] = (f32x4){0.f, 0.f, 0.f, 0.f};

  const int arow = wr * 64 + (lane & 15);           // + mi*16
  const int bcol = wc * 64 + (lane & 15);           // + ni*16
  const int kb8  = (lane >> 4) * 8;                 // k-byte within 32-chunk

  auto stage = [&](int buf, int ko) {
    #pragma unroll
    for (int rep = 0; rep < 2; ++rep) {             // A: 16 KB = 2 x (512*16B)
      int f  = rep * 8192 + tid * 16;
      int sf = f ^ (((f >> 7) & 7) << 4);
      global_to_lds16(Amat + (size_t)(row0 + (sf >> 6)) * K_DIM + ko + (sf & 63),
                      &sm.st.As[buf][f]);
    }
    {                                               // B: 8 KB = 1 x (512*16B)
      int f  = tid * 16;
      int sf = f ^ (((f >> 7) & 7) << 4);
      global_to_lds16(Bmat + (size_t)(col0 + (sf >> 6)) * K_DIM + ko + (sf & 63),
                      &sm.st.Bs[buf][f]);
    }
  };
  auto ld64 = [&](const unsigned char* base, int row, int kb) -> long {
    int f = row * 64 + kb;
    return *(const long*)(base + (f ^ (((f >> 7) & 7) << 4)));
  };

  stage(0, 0);
  __syncthreads();
  for (int t = 0; t < 16; ++t) {
    if (t < 15) stage((t + 1) & 1, (t + 1) * 64);   // issue next-tile loads FIRST
    const unsigned char* Ab = sm.st.As[t & 1];
    const unsigned char* Bb = sm.st.Bs[t & 1];
    __builtin_amdgcn_s_setprio(1);
    #pragma unroll
    for (int ks = 0; ks < 64; ks += 32) {
      long a[4], b[4];
      #pragma unroll
      for (int mi = 0; mi < 4; ++mi) a[mi] = ld64(Ab, arow + mi * 16, ks + kb8);
      #pragma unroll
      for (int ni = 0; ni < 4; ++ni) b[ni] = ld64(Bb, bcol + ni * 16, ks + kb8);
      #pragma unroll
      for (int mi = 0; mi < 4; ++mi)
        #pragma unroll
        for (int ni = 0; ni < 4; ++ni)
          acc[mi][ni] = __builtin_amdgcn_mfma_f32_16x16x32_fp8_fp8(a[mi], b[ni], acc[mi][ni], 0, 0, 0);
    }
    __builtin_amdgcn_s_setprio(0);
    __syncthreads();   // drains staging vmcnt AFTER compute: latency hidden
  }

  // ---- in-register epilogue: per-row max / sumexp over this wave's 64 cols,
  //      plus fused target-logit write. C/D layout: col=lane&15, row=(lane>>4)*4+j.
  const int l15 = lane & 15;
  float tc[4];
  #pragma unroll
  for (int ni = 0; ni < 4; ++ni)
    tc[ni] = tvec[col0 + wc * 64 + ni * 16 + l15];
  const int cbase = col0 + wc * 64 + l15;           // + ni*16

  #pragma unroll
  for (int mi = 0; mi < 4; ++mi) {
    #pragma unroll
    for (int j = 0; j < 4; ++j) {
      const int grow = row0 + wr * 64 + mi * 16 + ((lane >> 4) << 2) + j;
      const int d = T[grow] - cbase;                // match iff d == ni*16
      float z0 = acc[mi][0][j] - tc[0];
      float z1 = acc[mi][1][j] - tc[1];
      float z2 = acc[mi][2][j] - tc[2];
      float z3 = acc[mi][3][j] - tc[3];
      if (d == 0)  tgt[grow] = z0;
      if (d == 16) tgt[grow] = z1;
      if (d == 32) tgt[grow] = z2;
      if (d == 48) tgt[grow] = z3;
      float m = fmaxf(fmaxf(z0, z1), fmaxf(z2, z3));
      #pragma unroll
      for (int o = 1; o < 16; o <<= 1) m = fmaxf(m, __shfl_xor(m, o));
      float s = __expf(z0 - m) + __expf(z1 - m) + __expf(z2 - m) + __expf(z3 - m);
      #pragma unroll
      for (int o = 1; o < 16; o <<= 1) s += __shfl_xor(s, o);
      if (l15 == 0) {
        int rloc = wr * 64 + mi * 16 + ((lane >> 4) << 2) + j;
        sm.ms[rloc][wc][0] = m;
        sm.ms[rloc][wc][1] = s;
      }
    }
  }
  __syncthreads();
  if (tid < 256) {
    float m0 = sm.ms[tid][0][0], s0 = sm.ms[tid][0][1];
    float m1 = sm.ms[tid][1][0], s1 = sm.ms[tid][1][1];
    float M = fmaxf(m0, m1);
    float S = s0 * __expf(m0 - M) + s1 * __expf(m1 - M);
    Pm  [(size_t)(row0 + tid) * 64 + ct] = M;
    Psum[(size_t)(row0 + tid) * 64 + ct] = S;
  }
}

// ---------------------------------------------------------------------------
// K5a: 256-block LSE reduce (target dot now comes from the GEMM epilogue).
//      Block b: rows [b*16, b*16+16) -> ce partial (16 lanes/row, 1 float4
//      each over 64 partials); classes [b*32, b*32+32) -> kl partial.
// ---------------------------------------------------------------------------
__global__ __launch_bounds__(256) void k_red(const float* __restrict__ Pm,
                                             const float* __restrict__ Psum,
                                             const float* __restrict__ tgt,
                                             const float* __restrict__ klc,
                                             float* __restrict__ cep,
                                             float* __restrict__ klp) {
  const int b = blockIdx.x;
  const int tid = threadIdx.x;
  const int n = b * 16 + (tid >> 4);
  const int l4 = tid & 15;
  float4 pm = *(const float4*)(Pm   + (size_t)n * 64 + l4 * 4);
  float4 ps = *(const float4*)(Psum + (size_t)n * 64 + l4 * 4);
  float m = fmaxf(fmaxf(pm.x, pm.y), fmaxf(pm.z, pm.w));
  #pragma unroll
  for (int o = 1; o < 16; o <<= 1) m = fmaxf(m, __shfl_xor(m, o));
  float S = ps.x * __expf(pm.x - m) + ps.y * __expf(pm.y - m)
          + ps.z * __expf(pm.z - m) + ps.w * __expf(pm.w - m);
  #pragma unroll
  for (int o = 1; o < 16; o <<= 1) S += __shfl_xor(S, o);
  float ce = (l4 == 0) ? (m + logf(S) - tgt[n]) : 0.f;
  float kl = (tid < 32) ? klc[b * 32 + tid] : 0.f;
  ce = block_sum256(ce);
  kl = block_sum256(kl);
  if (tid == 0) { cep[b] = ce; klp[b] = kl; }
}

// K5b: final combine (1 block, 256 threads; 256 partials)
__global__ __launch_bounds__(256) void k_fin2(const float* __restrict__ cep,
                                              const float* __restrict__ klp,
                                              float* __restrict__ out) {
  const int tid = threadIdx.x;
  float ce = block_sum256(cep[tid]);
  float kl = block_sum256(klp[tid]);
  if (tid == 0) out[0] = ce / (float)N_ROWS + 0.2f * (kl / (float)N_CLS);
}

extern "C" void kernel_launch(void* const* d_in, const int* in_sizes, int n_in,
                              void* d_out, int out_size, void* d_ws, size_t ws_size,
                              hipStream_t stream) {
  const float* X          = (const float*)d_in[0];
  // d_in[1] = indices (unused by the reference loss)
  const int*   T          = (const int*)d_in[2];
  const float* proxies    = (const float*)d_in[3];
  const float* sigmas_inv = (const float*)d_in[4];

  char* ws = (char*)d_ws;
  unsigned char* Amat = (unsigned char*)ws;                            // 4 MiB
  unsigned char* Bmat = (unsigned char*)(ws + (4u << 20));             // 8 MiB
  float* tvec = (float*)(ws + (12u << 20));                            // 32 KiB
  float* klc  = (float*)(ws + (12u << 20) + (32u << 10));              // 32 KiB
  float* Pm   = (float*)(ws + (12u << 20) + (64u << 10));              // 1 MiB
  float* Psum = (float*)(ws + (13u << 20) + (64u << 10));              // 1 MiB
  float* tgt  = (float*)(ws + (14u << 20) + (64u << 10));              // 16 KiB
  float* cep  = (float*)(ws + (14u << 20) + (80u << 10));              // 1 KiB
  float* klp  = (float*)(ws + (14u << 20) + (84u << 10));              // 1 KiB
  float* out  = (float*)d_out;

  hipLaunchKernelGGL(k_prep,     dim3(N_CLS + N_ROWS), dim3(256), 0, stream,
                     proxies, sigmas_inv, X, Bmat, Amat, tvec, klc);
  hipLaunchKernelGGL(k_gemm_lse, dim3(1024),           dim3(512), 0, stream,
                     Amat, Bmat, tvec, T, Pm, Psum, tgt);
  hipLaunchKernelGGL(k_red,      dim3(256),            dim3(256), 0, stream,
                     Pm, Psum, tgt, klc, cep, klp);
  hipLaunchKernelGGL(k_fin2,     dim3(1),              dim3(256), 0, stream,
                     cep, klp, out);
}